// Round 12
// baseline (969.176 us; speedup 1.0000x reference)
//
#include <hip/hip_runtime.h>
#include <hip/hip_bf16.h>

#define B_ 4
#define S_ 2048
#define D_ 768
#define H_ 12
#define HD 64

typedef __attribute__((ext_vector_type(8))) short short8;
typedef __attribute__((ext_vector_type(4))) float f32x4;

__device__ __forceinline__ float fmapf(float x) { return x > 0.f ? x + 1.f : __expf(x); }

// fp32 -> bf16 round-to-nearest-even (finite inputs only)
__device__ __forceinline__ unsigned short f2bu(float f) {
    unsigned u = __float_as_uint(f);
    u += 0x7FFFu + ((u >> 16) & 1u);
    return (unsigned short)(u >> 16);
}
__device__ __forceinline__ float bu2f(unsigned short v) {
    return __uint_as_float((unsigned)v << 16);
}

// ---------------------------------------------------------------------------
// Kernel 0: fp32 -> bf16 bulk convert (n % 4 == 0).
// ---------------------------------------------------------------------------
__global__ __launch_bounds__(256) void convert_bf16(const float* __restrict__ src,
                                                    unsigned short* __restrict__ dst,
                                                    int n) {
    int i = (blockIdx.x * 256 + threadIdx.x) * 4;
    if (i < n) {
        float4 v = *(const float4*)&src[i];
        ushort4 o;
        o.x = f2bu(v.x); o.y = f2bu(v.y); o.z = f2bu(v.z); o.w = f2bu(v.w);
        *(ushort4*)&dst[i] = o;
    }
}

// ---------------------------------------------------------------------------
// Kernel 1: qkv = x @ qkv_w.T via bf16 MFMA (16x16x32), fp32 accumulate.
// Inputs pre-converted to bf16; staging is pure uint4 copy (no VALU).
// ---------------------------------------------------------------------------
__global__ __launch_bounds__(256) void qkv_gemm_mfma(const unsigned short* __restrict__ xb,
                                                     const unsigned short* __restrict__ wb,
                                                     float* __restrict__ qf,
                                                     float* __restrict__ kf,
                                                     float* __restrict__ vv) {
    __shared__ short As[128][40];  // 128 x 32 bf16, +8 pad (80B row stride)
    __shared__ short Bs[128][40];
    const int K = 768;
    int n0 = blockIdx.x * 128, m0 = blockIdx.y * 128;
    int tid = threadIdx.x, lane = tid & 63, wave = tid >> 6;
    int wm = (wave & 1) * 64, wn = (wave >> 1) * 64;
    int quad = lane >> 4, l15 = lane & 15;
    int srow = tid >> 1, scol = (tid & 1) * 16;
    f32x4 acc[4][4];
#pragma unroll
    for (int i = 0; i < 4; i++)
#pragma unroll
        for (int j = 0; j < 4; j++) acc[i][j] = 0.f;

    for (int k0 = 0; k0 < K; k0 += 32) {
        const unsigned short* xp = xb + (size_t)(m0 + srow) * K + k0 + scol;
        const unsigned short* wp = wb + (size_t)(n0 + srow) * K + k0 + scol;
        uint4 xa0 = *(const uint4*)xp;
        uint4 xa1 = *(const uint4*)(xp + 8);
        uint4 wa0 = *(const uint4*)wp;
        uint4 wa1 = *(const uint4*)(wp + 8);
        *(uint4*)&As[srow][scol] = xa0;
        *(uint4*)&As[srow][scol + 8] = xa1;
        *(uint4*)&Bs[srow][scol] = wa0;
        *(uint4*)&Bs[srow][scol + 8] = wa1;
        __syncthreads();
        short8 af[4], bfr[4];
#pragma unroll
        for (int i = 0; i < 4; i++) af[i] = *(short8*)&As[wm + i * 16 + l15][quad * 8];
#pragma unroll
        for (int j = 0; j < 4; j++) bfr[j] = *(short8*)&Bs[wn + j * 16 + l15][quad * 8];
#pragma unroll
        for (int i = 0; i < 4; i++)
#pragma unroll
            for (int j = 0; j < 4; j++)
                acc[i][j] = __builtin_amdgcn_mfma_f32_16x16x32_bf16(af[i], bfr[j], acc[i][j], 0, 0, 0);
        __syncthreads();
    }
#pragma unroll
    for (int j = 0; j < 4; j++) {
        int col = n0 + wn + j * 16 + l15;
        int t3 = col / 768;
        int r = col - t3 * 768;
        int h = r >> 6, d = r & 63;
#pragma unroll
        for (int i = 0; i < 4; i++) {
#pragma unroll
            for (int rr = 0; rr < 4; rr++) {
                int m = m0 + wm + i * 16 + quad * 4 + rr;
                int b = m >> 11, s = m & 2047;
                size_t dst = (((size_t)(b * H_ + h) * S_) + s) * HD + d;
                float val = acc[i][j][rr];
                if (t3 == 0)
                    qf[dst] = fmapf(val);
                else if (t3 == 1)
                    kf[dst] = fmapf(val);
                else
                    vv[dst] = val;
            }
        }
    }
}

// ---------------------------------------------------------------------------
// Kernel 2a: partial kv states. Grid = 48 bh * 8 chunks (256 tokens each).
// ---------------------------------------------------------------------------
__global__ __launch_bounds__(256) void band_partial(const float* __restrict__ kf,
                                                    const float* __restrict__ vv,
                                                    float* __restrict__ pkv,
                                                    float* __restrict__ pks) {
    int bh = blockIdx.x >> 3, chunk = blockIdx.x & 7;
    int sbase = chunk * 256;
    const float* kfp = kf + (size_t)bh * S_ * HD + (size_t)sbase * HD;
    const float* vp = vv + (size_t)bh * S_ * HD + (size_t)sbase * HD;
    __shared__ float kt[16][64];
    __shared__ float vt[16][64];
    int tid = threadIdx.x;
    int d = tid >> 2, eg = tid & 3, e0 = eg * 16;
    float accg[16], accs[16];
#pragma unroll
    for (int i = 0; i < 16; i++) { accg[i] = 0.f; accs[i] = 0.f; }
    float ksg = 0.f, kss = 0.f;
    for (int s0 = 0; s0 < 256; s0 += 16) {
        for (int i = tid; i < 1024; i += 256) {
            kt[i >> 6][i & 63] = kfp[(size_t)s0 * HD + i];
            vt[i >> 6][i & 63] = vp[(size_t)s0 * HD + i];
        }
        __syncthreads();
#pragma unroll 4
        for (int ss = 0; ss < 16; ss++) {
            float kd = kt[ss][d];
            bool str = ((sbase + s0 + ss) % 3) == 0;  // block-uniform
            ksg += kd;
            if (str) kss += kd;
#pragma unroll
            for (int i = 0; i < 16; i++) {
                float ve = vt[ss][e0 + i];
                accg[i] += kd * ve;
                if (str) accs[i] += kd * ve;
            }
        }
        __syncthreads();
    }
    float* pg = pkv + (size_t)blockIdx.x * 2 * 4096;
#pragma unroll
    for (int i = 0; i < 16; i++) pg[d * 64 + e0 + i] = accg[i];
#pragma unroll
    for (int i = 0; i < 16; i++) pg[4096 + d * 64 + e0 + i] = accs[i];
    if (eg == 0) {
        pks[blockIdx.x * 128 + d] = ksg;
        pks[blockIdx.x * 128 + 64 + d] = kss;
    }
}

// ---------------------------------------------------------------------------
// Kernel 2b: reduce partials + anchor outputs. Grid = 48 bh * 4 e-blocks.
// ---------------------------------------------------------------------------
__global__ __launch_bounds__(256) void band_reduce(const float* __restrict__ pkv,
                                                   const float* __restrict__ pks,
                                                   const float* __restrict__ aq,
                                                   float* __restrict__ kvs,
                                                   float* __restrict__ ksums,
                                                   float* __restrict__ aout) {
    int bh = blockIdx.x >> 2, eb = blockIdx.x & 3, e0 = eb * 16;
    int h = bh % H_;
    __shared__ float kvgL[64][17];
    __shared__ float ksgL[64];
    __shared__ float anorm[12];
    int tid = threadIdx.x;
    for (int idx = tid; idx < 1024; idx += 256) {
        int d = idx >> 4, j = idx & 15;
        float sg = 0.f, ss = 0.f;
        const float* p = pkv + (size_t)(bh * 8) * 2 * 4096 + d * 64 + e0 + j;
#pragma unroll 4
        for (int c = 0; c < 8; c++) {
            sg += p[0];
            ss += p[4096];
            p += 2 * 4096;
        }
        kvgL[d][j] = sg;
        kvs[(size_t)bh * 4096 + d * 64 + e0 + j] = ss;
    }
    if (tid < 64) {
        float sg = 0.f, ss = 0.f;
#pragma unroll 4
        for (int c = 0; c < 8; c++) {
            sg += pks[(bh * 8 + c) * 128 + tid];
            ss += pks[(bh * 8 + c) * 128 + 64 + tid];
        }
        ksgL[tid] = sg;
        if (eb == 0) ksums[bh * 64 + tid] = ss;
    }
    __syncthreads();
    if (tid < 12) {
        float nrm = 0.f;
        for (int dd = 0; dd < 64; dd++)
            nrm += fmapf(aq[h * 768 + tid * 64 + dd]) * ksgL[dd];
        anorm[tid] = fmaxf(nrm, 1e-6f);
    }
    __syncthreads();
    if (tid < 192) {
        int a = tid >> 4, j = tid & 15;
        float acc = 0.f;
        for (int dd = 0; dd < 64; dd++)
            acc += fmapf(aq[h * 768 + a * 64 + dd]) * kvgL[dd][j];
        aout[(size_t)bh * 768 + a * 64 + e0 + j] = acc / anorm[a];
    }
}

// ---------------------------------------------------------------------------
// Kernel 3: combine. Round-10 skeleton (scalar phase A, 3 blocks/CU) with
// ONE change: stride-band matvec restructured dd-outer, 16 accumulators,
// kvsL read once per dd (b32/lane) + qft read as wave-broadcast b128.
// Writes attn as bf16. LDS ~53.8 KB.
// ---------------------------------------------------------------------------
__global__ __launch_bounds__(256) void combine(const float* __restrict__ qf,
                                               const float* __restrict__ kf,
                                               const float* __restrict__ vv,
                                               const float* __restrict__ aq,
                                               const float* __restrict__ kvs,
                                               const float* __restrict__ ksums,
                                               const float* __restrict__ aout,
                                               const float* __restrict__ wlp,
                                               const float* __restrict__ wsp,
                                               const float* __restrict__ wgp,
                                               unsigned short* __restrict__ attnb) {
    __shared__ __attribute__((aligned(16))) float qft[64][68];
    __shared__ __attribute__((aligned(16))) float kvsL[64][68];
    __shared__ unsigned short kftb[75][68];
    __shared__ unsigned short aoutb[12][68];
    __shared__ float qkl[64][12];
    __shared__ float qkg[64][12];
    __shared__ float ksumL[64];
    __shared__ float nl[64], ng[64], ns[64];
    int bh = blockIdx.x >> 5, stile = blockIdx.x & 31;
    int b = bh / H_, h = bh % H_;
    int s0 = stile * 64;
    int tid = threadIdx.x;
    const float* qfp = qf + (size_t)bh * S_ * HD;
    const float* kfp = kf + (size_t)bh * S_ * HD;
    const float* vp = vv + (size_t)bh * S_ * HD;
    float a0 = wlp[0], a1 = wsp[0], a2 = wgp[0];
    float mx = fmaxf(a0, fmaxf(a1, a2));
    float ew0 = __expf(a0 - mx), ew1 = __expf(a1 - mx), ew2 = __expf(a2 - mx);
    float inv = 1.f / (ew0 + ew1 + ew2);
    float wl = ew0 * inv, wsb = ew1 * inv, wg = ew2 * inv;
    // stage (scalar, as round 10)
    for (int i = tid; i < 4096; i += 256) {
        int r = i >> 6, c = i & 63;
        kvsL[r][c] = kvs[(size_t)bh * 4096 + i];
        qft[r][c] = qfp[(size_t)s0 * HD + i];
    }
    for (int i = tid; i < 75 * 64; i += 256) {
        int row = i >> 6, c = i & 63;
        int gs = s0 + row - 6;
        float kv_ = (gs >= 0 && gs < S_) ? kfp[(size_t)gs * HD + c] : 1.0f;
        kftb[row][c] = f2bu(kv_);
    }
    for (int i = tid; i < 768; i += 256)
        aoutb[i >> 6][i & 63] = f2bu(aout[(size_t)bh * 768 + i]);
    if (tid < 64) ksumL[tid] = ksums[bh * 64 + tid];
    __syncthreads();
    // phase A (scalar, as round 10)
    for (int r = tid; r < 64 * 25; r += 256) {
        int token = r / 25;
        int which = r - token * 25;
        float acc = 0.f;
        if (which < 12) {
            int row = token + which;
#pragma unroll 8
            for (int dd = 0; dd < 64; dd++) acc += qft[token][dd] * bu2f(kftb[row][dd]);
            qkl[token][which] = acc;
        } else if (which < 24) {
            int a = which - 12;
            const float* ap = aq + h * 768 + a * 64;
#pragma unroll 8
            for (int dd = 0; dd < 64; dd++) acc += qft[token][dd] * fmapf(ap[dd]);
            qkg[token][a] = acc;
        } else {
#pragma unroll 8
            for (int dd = 0; dd < 64; dd++) acc += qft[token][dd] * ksumL[dd];
            ns[token] = acc;
        }
    }
    __syncthreads();
    if (tid < 64) {
        float sl = 0.f, sg = 0.f;
#pragma unroll
        for (int j = 0; j < 12; j++) { sl += qkl[tid][j]; sg += qkg[tid][j]; }
        nl[tid] = fmaxf(sl, 1e-6f);
        ng[tid] = fmaxf(sg, 1e-6f);
        ns[tid] = fmaxf(ns[tid], 1e-6f);
    }
    __syncthreads();
    // phase B: e = lane, tokens tg+4t. Stride-band matvec dd-outer:
    // per 4-dd block: 4 per-lane kvsL b32 reads + 16 broadcast qft b128 reads.
    int e = tid & 63, tg = tid >> 6;
    float os[16];
#pragma unroll
    for (int t = 0; t < 16; t++) os[t] = 0.f;
#pragma unroll
    for (int d4 = 0; d4 < 16; d4++) {
        float k_0 = kvsL[d4 * 4 + 0][e];
        float k_1 = kvsL[d4 * 4 + 1][e];
        float k_2 = kvsL[d4 * 4 + 2][e];
        float k_3 = kvsL[d4 * 4 + 3][e];
#pragma unroll
        for (int t = 0; t < 16; t++) {
            float4 q = *(const float4*)&qft[tg + t * 4][d4 * 4];
            os[t] += q.x * k_0 + q.y * k_1 + q.z * k_2 + q.w * k_3;
        }
    }
#pragma unroll
    for (int t = 0; t < 16; t++) {
        int token = tg + t * 4;
        float ol = 0.f;
#pragma unroll
        for (int j = 0; j < 12; j++) {
            int gs = s0 + token + j - 6;  // uniform per wave
            float vval = (gs >= 0 && gs < S_) ? vp[(size_t)gs * HD + e] : 0.f;
            ol += qkl[token][j] * vval;
        }
        float og = 0.f;
#pragma unroll
        for (int a = 0; a < 12; a++) og += qkg[token][a] * bu2f(aoutb[a][e]);
        float res = wl * ol / nl[token] + wsb * os[t] / ns[token] + wg * og / ng[token];
        attnb[((size_t)(b * S_ + s0 + token)) * 768 + h * 64 + e] = f2bu(res);
    }
}

// ---------------------------------------------------------------------------
// Kernel 4: out = attn(bf16) @ out_w.T via bf16 MFMA -> fp32 out.
// ---------------------------------------------------------------------------
__global__ __launch_bounds__(256) void out_gemm_mfma(const unsigned short* __restrict__ attnb,
                                                     const unsigned short* __restrict__ wb,
                                                     float* __restrict__ out) {
    __shared__ short As[128][40];
    __shared__ short Bs[128][40];
    const int K = 768;
    int n0 = blockIdx.x * 128, m0 = blockIdx.y * 128;
    int tid = threadIdx.x, lane = tid & 63, wave = tid >> 6;
    int wm = (wave & 1) * 64, wn = (wave >> 1) * 64;
    int quad = lane >> 4, l15 = lane & 15;
    int srow = tid >> 1, scol = (tid & 1) * 16;
    f32x4 acc[4][4];
#pragma unroll
    for (int i = 0; i < 4; i++)
#pragma unroll
        for (int j = 0; j < 4; j++) acc[i][j] = 0.f;

    for (int k0 = 0; k0 < K; k0 += 32) {
        const unsigned short* ap = attnb + (size_t)(m0 + srow) * K + k0 + scol;
        const unsigned short* wp = wb + (size_t)(n0 + srow) * K + k0 + scol;
        uint4 a0 = *(const uint4*)ap;
        uint4 a1 = *(const uint4*)(ap + 8);
        uint4 w0 = *(const uint4*)wp;
        uint4 w1 = *(const uint4*)(wp + 8);
        *(uint4*)&As[srow][scol] = a0;
        *(uint4*)&As[srow][scol + 8] = a1;
        *(uint4*)&Bs[srow][scol] = w0;
        *(uint4*)&Bs[srow][scol + 8] = w1;
        __syncthreads();
        short8 af[4], bfr[4];
#pragma unroll
        for (int i = 0; i < 4; i++) af[i] = *(short8*)&As[wm + i * 16 + l15][quad * 8];
#pragma unroll
        for (int j = 0; j < 4; j++) bfr[j] = *(short8*)&Bs[wn + j * 16 + l15][quad * 8];
#pragma unroll
        for (int i = 0; i < 4; i++)
#pragma unroll
            for (int j = 0; j < 4; j++)
                acc[i][j] = __builtin_amdgcn_mfma_f32_16x16x32_bf16(af[i], bfr[j], acc[i][j], 0, 0, 0);
        __syncthreads();
    }
#pragma unroll
    for (int j = 0; j < 4; j++) {
        int col = n0 + wn + j * 16 + l15;
#pragma unroll
        for (int i = 0; i < 4; i++) {
#pragma unroll
            for (int rr = 0; rr < 4; rr++) {
                int m = m0 + wm + i * 16 + quad * 4 + rr;
                out[(size_t)m * 768 + col] = acc[i][j][rr];
            }
        }
    }
}

extern "C" void kernel_launch(void* const* d_in, const int* in_sizes, int n_in,
                              void* d_out, int out_size, void* d_ws, size_t ws_size,
                              hipStream_t stream) {
    const float* x = (const float*)d_in[0];
    const float* qkvw = (const float*)d_in[1];
    const float* outw = (const float*)d_in[2];
    const float* aq = (const float*)d_in[3];
    const float* wlp = (const float*)d_in[4];
    const float* wsp = (const float*)d_in[5];
    const float* wgp = (const float*)d_in[6];

    float* ws = (float*)d_ws;
    const size_t NBH = (size_t)B_ * H_ * S_ * HD;  // 6,291,456
    float* qf = ws;
    float* kf = qf + NBH;
    float* vv = kf + NBH;
    float* attn_region = vv + NBH;       // NBH floats; multi-use scratch
    float* kvs = attn_region + NBH;      // 48*4096
    float* ksums = kvs + 48 * 4096;      // 48*64
    float* aout = ksums + 48 * 64;       // 48*768
    // Lifetimes inside attn_region (NBH floats):
    //  [0, 3145728)           xb (bf16 x)      : convert .. qkv_gemm
    //  [3145728, 4030464)     wb (bf16 qkv_w)  : convert .. qkv_gemm
    //  [4030464, 4325376)     outwb (bf16)     : convert .. out_gemm
    //  [0, 3145728)           pkv              : band_partial .. band_reduce
    //  [3145728, 3194880)     pks              : band_partial .. band_reduce
    //  [0, 3145728)           attnb (bf16 attn): combine .. out_gemm
    unsigned short* xb = (unsigned short*)attn_region;
    unsigned short* wb = (unsigned short*)(attn_region + 3145728);
    unsigned short* outwb = (unsigned short*)(attn_region + 3145728 + 884736);
    float* pkv = attn_region;
    float* pks = attn_region + 3145728;
    unsigned short* attnb = (unsigned short*)attn_region;

    convert_bf16<<<6144, 256, 0, stream>>>(x, xb, 6291456);
    convert_bf16<<<1728, 256, 0, stream>>>(qkvw, wb, 1769472);
    convert_bf16<<<576, 256, 0, stream>>>(outw, outwb, 589824);
    qkv_gemm_mfma<<<dim3(18, 64), 256, 0, stream>>>(xb, wb, qf, kf, vv);
    band_partial<<<48 * 8, 256, 0, stream>>>(kf, vv, pkv, pks);
    band_reduce<<<48 * 4, 256, 0, stream>>>(pkv, pks, aq, kvs, ksums, aout);
    combine<<<48 * 32, 256, 0, stream>>>(qf, kf, vv, aq, kvs, ksums, aout, wlp, wsp, wgp, attnb);
    out_gemm_mfma<<<dim3(6, 64), 256, 0, stream>>>(attnb, outwb, (float*)d_out);
}

// Round 13
// 415.428 us; speedup vs baseline: 2.3330x; 2.3330x over previous
//
#include <hip/hip_runtime.h>
#include <hip/hip_bf16.h>

#define B_ 4
#define S_ 2048
#define D_ 768
#define H_ 12
#define HD 64

typedef __attribute__((ext_vector_type(8))) short short8;
typedef __attribute__((ext_vector_type(4))) float f32x4;

__device__ __forceinline__ float fmapf(float x) { return x > 0.f ? x + 1.f : __expf(x); }

// fp32 -> bf16 round-to-nearest-even (finite inputs only)
__device__ __forceinline__ unsigned short f2bu(float f) {
    unsigned u = __float_as_uint(f);
    u += 0x7FFFu + ((u >> 16) & 1u);
    return (unsigned short)(u >> 16);
}
__device__ __forceinline__ float bu2f(unsigned short v) {
    return __uint_as_float((unsigned)v << 16);
}

// ---------------------------------------------------------------------------
// Kernel 0: fp32 -> bf16 bulk convert (n % 4 == 0).
// ---------------------------------------------------------------------------
__global__ __launch_bounds__(256) void convert_bf16(const float* __restrict__ src,
                                                    unsigned short* __restrict__ dst,
                                                    int n) {
    int i = (blockIdx.x * 256 + threadIdx.x) * 4;
    if (i < n) {
        float4 v = *(const float4*)&src[i];
        ushort4 o;
        o.x = f2bu(v.x); o.y = f2bu(v.y); o.z = f2bu(v.z); o.w = f2bu(v.w);
        *(ushort4*)&dst[i] = o;
    }
}

// ---------------------------------------------------------------------------
// Kernel 1: qkv = x @ qkv_w.T via bf16 MFMA (16x16x32), fp32 accumulate.
// Inputs pre-converted to bf16; staging is pure uint4 copy (no VALU).
// ---------------------------------------------------------------------------
__global__ __launch_bounds__(256) void qkv_gemm_mfma(const unsigned short* __restrict__ xb,
                                                     const unsigned short* __restrict__ wb,
                                                     float* __restrict__ qf,
                                                     float* __restrict__ kf,
                                                     float* __restrict__ vv) {
    __shared__ short As[128][40];  // 128 x 32 bf16, +8 pad (80B row stride)
    __shared__ short Bs[128][40];
    const int K = 768;
    int n0 = blockIdx.x * 128, m0 = blockIdx.y * 128;
    int tid = threadIdx.x, lane = tid & 63, wave = tid >> 6;
    int wm = (wave & 1) * 64, wn = (wave >> 1) * 64;
    int quad = lane >> 4, l15 = lane & 15;
    int srow = tid >> 1, scol = (tid & 1) * 16;
    f32x4 acc[4][4];
#pragma unroll
    for (int i = 0; i < 4; i++)
#pragma unroll
        for (int j = 0; j < 4; j++) acc[i][j] = 0.f;

    for (int k0 = 0; k0 < K; k0 += 32) {
        const unsigned short* xp = xb + (size_t)(m0 + srow) * K + k0 + scol;
        const unsigned short* wp = wb + (size_t)(n0 + srow) * K + k0 + scol;
        uint4 xa0 = *(const uint4*)xp;
        uint4 xa1 = *(const uint4*)(xp + 8);
        uint4 wa0 = *(const uint4*)wp;
        uint4 wa1 = *(const uint4*)(wp + 8);
        *(uint4*)&As[srow][scol] = xa0;
        *(uint4*)&As[srow][scol + 8] = xa1;
        *(uint4*)&Bs[srow][scol] = wa0;
        *(uint4*)&Bs[srow][scol + 8] = wa1;
        __syncthreads();
        short8 af[4], bfr[4];
#pragma unroll
        for (int i = 0; i < 4; i++) af[i] = *(short8*)&As[wm + i * 16 + l15][quad * 8];
#pragma unroll
        for (int j = 0; j < 4; j++) bfr[j] = *(short8*)&Bs[wn + j * 16 + l15][quad * 8];
#pragma unroll
        for (int i = 0; i < 4; i++)
#pragma unroll
            for (int j = 0; j < 4; j++)
                acc[i][j] = __builtin_amdgcn_mfma_f32_16x16x32_bf16(af[i], bfr[j], acc[i][j], 0, 0, 0);
        __syncthreads();
    }
#pragma unroll
    for (int j = 0; j < 4; j++) {
        int col = n0 + wn + j * 16 + l15;
        int t3 = col / 768;
        int r = col - t3 * 768;
        int h = r >> 6, d = r & 63;
#pragma unroll
        for (int i = 0; i < 4; i++) {
#pragma unroll
            for (int rr = 0; rr < 4; rr++) {
                int m = m0 + wm + i * 16 + quad * 4 + rr;
                int b = m >> 11, s = m & 2047;
                size_t dst = (((size_t)(b * H_ + h) * S_) + s) * HD + d;
                float val = acc[i][j][rr];
                if (t3 == 0)
                    qf[dst] = fmapf(val);
                else if (t3 == 1)
                    kf[dst] = fmapf(val);
                else
                    vv[dst] = val;
            }
        }
    }
}

// ---------------------------------------------------------------------------
// Kernel 2a: partial kv states. Grid = 48 bh * 8 chunks (256 tokens each).
// ---------------------------------------------------------------------------
__global__ __launch_bounds__(256) void band_partial(const float* __restrict__ kf,
                                                    const float* __restrict__ vv,
                                                    float* __restrict__ pkv,
                                                    float* __restrict__ pks) {
    int bh = blockIdx.x >> 3, chunk = blockIdx.x & 7;
    int sbase = chunk * 256;
    const float* kfp = kf + (size_t)bh * S_ * HD + (size_t)sbase * HD;
    const float* vp = vv + (size_t)bh * S_ * HD + (size_t)sbase * HD;
    __shared__ float kt[16][64];
    __shared__ float vt[16][64];
    int tid = threadIdx.x;
    int d = tid >> 2, eg = tid & 3, e0 = eg * 16;
    float accg[16], accs[16];
#pragma unroll
    for (int i = 0; i < 16; i++) { accg[i] = 0.f; accs[i] = 0.f; }
    float ksg = 0.f, kss = 0.f;
    for (int s0 = 0; s0 < 256; s0 += 16) {
        for (int i = tid; i < 1024; i += 256) {
            kt[i >> 6][i & 63] = kfp[(size_t)s0 * HD + i];
            vt[i >> 6][i & 63] = vp[(size_t)s0 * HD + i];
        }
        __syncthreads();
#pragma unroll 4
        for (int ss = 0; ss < 16; ss++) {
            float kd = kt[ss][d];
            bool str = ((sbase + s0 + ss) % 3) == 0;  // block-uniform
            ksg += kd;
            if (str) kss += kd;
#pragma unroll
            for (int i = 0; i < 16; i++) {
                float ve = vt[ss][e0 + i];
                accg[i] += kd * ve;
                if (str) accs[i] += kd * ve;
            }
        }
        __syncthreads();
    }
    float* pg = pkv + (size_t)blockIdx.x * 2 * 4096;
#pragma unroll
    for (int i = 0; i < 16; i++) pg[d * 64 + e0 + i] = accg[i];
#pragma unroll
    for (int i = 0; i < 16; i++) pg[4096 + d * 64 + e0 + i] = accs[i];
    if (eg == 0) {
        pks[blockIdx.x * 128 + d] = ksg;
        pks[blockIdx.x * 128 + 64 + d] = kss;
    }
}

// ---------------------------------------------------------------------------
// Kernel 2b: reduce partials + anchor outputs. Grid = 48 bh * 4 e-blocks.
// ---------------------------------------------------------------------------
__global__ __launch_bounds__(256) void band_reduce(const float* __restrict__ pkv,
                                                   const float* __restrict__ pks,
                                                   const float* __restrict__ aq,
                                                   float* __restrict__ kvs,
                                                   float* __restrict__ ksums,
                                                   float* __restrict__ aout) {
    int bh = blockIdx.x >> 2, eb = blockIdx.x & 3, e0 = eb * 16;
    int h = bh % H_;
    __shared__ float kvgL[64][17];
    __shared__ float ksgL[64];
    __shared__ float anorm[12];
    int tid = threadIdx.x;
    for (int idx = tid; idx < 1024; idx += 256) {
        int d = idx >> 4, j = idx & 15;
        float sg = 0.f, ss = 0.f;
        const float* p = pkv + (size_t)(bh * 8) * 2 * 4096 + d * 64 + e0 + j;
#pragma unroll 4
        for (int c = 0; c < 8; c++) {
            sg += p[0];
            ss += p[4096];
            p += 2 * 4096;
        }
        kvgL[d][j] = sg;
        kvs[(size_t)bh * 4096 + d * 64 + e0 + j] = ss;
    }
    if (tid < 64) {
        float sg = 0.f, ss = 0.f;
#pragma unroll 4
        for (int c = 0; c < 8; c++) {
            sg += pks[(bh * 8 + c) * 128 + tid];
            ss += pks[(bh * 8 + c) * 128 + 64 + tid];
        }
        ksgL[tid] = sg;
        if (eb == 0) ksums[bh * 64 + tid] = ss;
    }
    __syncthreads();
    if (tid < 12) {
        float nrm = 0.f;
        for (int dd = 0; dd < 64; dd++)
            nrm += fmapf(aq[h * 768 + tid * 64 + dd]) * ksgL[dd];
        anorm[tid] = fmaxf(nrm, 1e-6f);
    }
    __syncthreads();
    if (tid < 192) {
        int a = tid >> 4, j = tid & 15;
        float acc = 0.f;
        for (int dd = 0; dd < 64; dd++)
            acc += fmapf(aq[h * 768 + a * 64 + dd]) * kvgL[dd][j];
        aout[(size_t)bh * 768 + a * 64 + e0 + j] = acc / anorm[a];
    }
}

// ---------------------------------------------------------------------------
// Kernel 3: combine. EXACT round-10 structure (149 us, 68 VGPR, 3 blocks/CU);
// only delta: final store is bf16 (for the MFMA out-GEMM). LDS ~53.8 KB.
// NOTE: two attempts to vectorize phase B (r11: float4 e-tiling, r12:
// dd-outer os[16]) both blew VGPR (216/256) and regressed — do not revisit
// without -Rpass-analysis showing VGPR < 170.
// ---------------------------------------------------------------------------
__global__ __launch_bounds__(256) void combine(const float* __restrict__ qf,
                                               const float* __restrict__ kf,
                                               const float* __restrict__ vv,
                                               const float* __restrict__ aq,
                                               const float* __restrict__ kvs,
                                               const float* __restrict__ ksums,
                                               const float* __restrict__ aout,
                                               const float* __restrict__ wlp,
                                               const float* __restrict__ wsp,
                                               const float* __restrict__ wgp,
                                               unsigned short* __restrict__ attnb) {
    __shared__ float kvsL[64][65];
    __shared__ float qft[64][65];
    __shared__ unsigned short kftb[75][66];  // bf16 local-key tile
    __shared__ float aoutL[12][64];
    __shared__ float qkl[64][12];
    __shared__ float qkg[64][12];
    __shared__ float ksumL[64];
    __shared__ float nl[64], ng[64], ns[64];
    int bh = blockIdx.x >> 5, stile = blockIdx.x & 31;
    int b = bh / H_, h = bh % H_;
    int s0 = stile * 64;
    int tid = threadIdx.x;
    const float* qfp = qf + (size_t)bh * S_ * HD;
    const float* kfp = kf + (size_t)bh * S_ * HD;
    const float* vp = vv + (size_t)bh * S_ * HD;
    float a0 = wlp[0], a1 = wsp[0], a2 = wgp[0];
    float mx = fmaxf(a0, fmaxf(a1, a2));
    float ew0 = __expf(a0 - mx), ew1 = __expf(a1 - mx), ew2 = __expf(a2 - mx);
    float inv = 1.f / (ew0 + ew1 + ew2);
    float wl = ew0 * inv, wsb = ew1 * inv, wg = ew2 * inv;
    for (int i = tid; i < 4096; i += 256) {
        kvsL[i >> 6][i & 63] = kvs[(size_t)bh * 4096 + i];
        qft[i >> 6][i & 63] = qfp[(size_t)s0 * HD + i];
    }
    for (int i = tid; i < 75 * 64; i += 256) {
        int row = i >> 6, c = i & 63;
        int gs = s0 + row - 6;
        float kv_ = (gs >= 0 && gs < S_) ? kfp[(size_t)gs * HD + c] : 1.0f;
        kftb[row][c] = f2bu(kv_);
    }
    if (tid < 64) ksumL[tid] = ksums[bh * 64 + tid];
    for (int i = tid; i < 768; i += 256) aoutL[i >> 6][i & 63] = aout[(size_t)bh * 768 + i];
    __syncthreads();
    for (int r = tid; r < 64 * 25; r += 256) {
        int token = r / 25;
        int which = r - token * 25;
        float acc = 0.f;
        if (which < 12) {
            int row = token + which;
#pragma unroll 8
            for (int dd = 0; dd < 64; dd++) acc += qft[token][dd] * bu2f(kftb[row][dd]);
            qkl[token][which] = acc;
        } else if (which < 24) {
            int a = which - 12;
            const float* ap = aq + h * 768 + a * 64;
#pragma unroll 8
            for (int dd = 0; dd < 64; dd++) acc += qft[token][dd] * fmapf(ap[dd]);
            qkg[token][a] = acc;
        } else {
#pragma unroll 8
            for (int dd = 0; dd < 64; dd++) acc += qft[token][dd] * ksumL[dd];
            ns[token] = acc;
        }
    }
    __syncthreads();
    if (tid < 64) {
        float sl = 0.f, sg = 0.f;
#pragma unroll
        for (int j = 0; j < 12; j++) { sl += qkl[tid][j]; sg += qkg[tid][j]; }
        nl[tid] = fmaxf(sl, 1e-6f);
        ng[tid] = fmaxf(sg, 1e-6f);
        ns[tid] = fmaxf(ns[tid], 1e-6f);
    }
    __syncthreads();
    int e = tid & 63, tg = tid >> 6;
    for (int token = tg; token < 64; token += 4) {
        float ol = 0.f;
#pragma unroll
        for (int j = 0; j < 12; j++) {
            int gs = s0 + token + j - 6;  // uniform per wave
            float vval = (gs >= 0 && gs < S_) ? vp[(size_t)gs * HD + e] : 0.f;
            ol += qkl[token][j] * vval;
        }
        float os = 0.f;
#pragma unroll 16
        for (int dd = 0; dd < 64; dd++) os += qft[token][dd] * kvsL[dd][e];
        float og = 0.f;
#pragma unroll
        for (int a = 0; a < 12; a++) og += qkg[token][a] * aoutL[a][e];
        float res = wl * ol / nl[token] + wsb * os / ns[token] + wg * og / ng[token];
        attnb[((size_t)(b * S_ + s0 + token)) * 768 + h * 64 + e] = f2bu(res);
    }
}

// ---------------------------------------------------------------------------
// Kernel 4: out = attn(bf16) @ out_w.T via bf16 MFMA -> fp32 out.
// ---------------------------------------------------------------------------
__global__ __launch_bounds__(256) void out_gemm_mfma(const unsigned short* __restrict__ attnb,
                                                     const unsigned short* __restrict__ wb,
                                                     float* __restrict__ out) {
    __shared__ short As[128][40];
    __shared__ short Bs[128][40];
    const int K = 768;
    int n0 = blockIdx.x * 128, m0 = blockIdx.y * 128;
    int tid = threadIdx.x, lane = tid & 63, wave = tid >> 6;
    int wm = (wave & 1) * 64, wn = (wave >> 1) * 64;
    int quad = lane >> 4, l15 = lane & 15;
    int srow = tid >> 1, scol = (tid & 1) * 16;
    f32x4 acc[4][4];
#pragma unroll
    for (int i = 0; i < 4; i++)
#pragma unroll
        for (int j = 0; j < 4; j++) acc[i][j] = 0.f;

    for (int k0 = 0; k0 < K; k0 += 32) {
        const unsigned short* ap = attnb + (size_t)(m0 + srow) * K + k0 + scol;
        const unsigned short* wp = wb + (size_t)(n0 + srow) * K + k0 + scol;
        uint4 a0 = *(const uint4*)ap;
        uint4 a1 = *(const uint4*)(ap + 8);
        uint4 w0 = *(const uint4*)wp;
        uint4 w1 = *(const uint4*)(wp + 8);
        *(uint4*)&As[srow][scol] = a0;
        *(uint4*)&As[srow][scol + 8] = a1;
        *(uint4*)&Bs[srow][scol] = w0;
        *(uint4*)&Bs[srow][scol + 8] = w1;
        __syncthreads();
        short8 af[4], bfr[4];
#pragma unroll
        for (int i = 0; i < 4; i++) af[i] = *(short8*)&As[wm + i * 16 + l15][quad * 8];
#pragma unroll
        for (int j = 0; j < 4; j++) bfr[j] = *(short8*)&Bs[wn + j * 16 + l15][quad * 8];
#pragma unroll
        for (int i = 0; i < 4; i++)
#pragma unroll
            for (int j = 0; j < 4; j++)
                acc[i][j] = __builtin_amdgcn_mfma_f32_16x16x32_bf16(af[i], bfr[j], acc[i][j], 0, 0, 0);
        __syncthreads();
    }
#pragma unroll
    for (int j = 0; j < 4; j++) {
        int col = n0 + wn + j * 16 + l15;
#pragma unroll
        for (int i = 0; i < 4; i++) {
#pragma unroll
            for (int rr = 0; rr < 4; rr++) {
                int m = m0 + wm + i * 16 + quad * 4 + rr;
                out[(size_t)m * 768 + col] = acc[i][j][rr];
            }
        }
    }
}

extern "C" void kernel_launch(void* const* d_in, const int* in_sizes, int n_in,
                              void* d_out, int out_size, void* d_ws, size_t ws_size,
                              hipStream_t stream) {
    const float* x = (const float*)d_in[0];
    const float* qkvw = (const float*)d_in[1];
    const float* outw = (const float*)d_in[2];
    const float* aq = (const float*)d_in[3];
    const float* wlp = (const float*)d_in[4];
    const float* wsp = (const float*)d_in[5];
    const float* wgp = (const float*)d_in[6];

    float* ws = (float*)d_ws;
    const size_t NBH = (size_t)B_ * H_ * S_ * HD;  // 6,291,456
    float* qf = ws;
    float* kf = qf + NBH;
    float* vv = kf + NBH;
    float* attn_region = vv + NBH;       // NBH floats; multi-use scratch
    float* kvs = attn_region + NBH;      // 48*4096
    float* ksums = kvs + 48 * 4096;      // 48*64
    float* aout = ksums + 48 * 64;       // 48*768
    // Lifetimes inside attn_region (NBH floats):
    //  [0, 3145728)           xb (bf16 x)      : convert .. qkv_gemm
    //  [3145728, 4030464)     wb (bf16 qkv_w)  : convert .. qkv_gemm
    //  [4030464, 4325376)     outwb (bf16)     : convert .. out_gemm
    //  [0, 3145728)           pkv              : band_partial .. band_reduce
    //  [3145728, 3194880)     pks              : band_partial .. band_reduce
    //  [0, 3145728)           attnb (bf16 attn): combine .. out_gemm
    unsigned short* xb = (unsigned short*)attn_region;
    unsigned short* wb = (unsigned short*)(attn_region + 3145728);
    unsigned short* outwb = (unsigned short*)(attn_region + 3145728 + 884736);
    float* pkv = attn_region;
    float* pks = attn_region + 3145728;
    unsigned short* attnb = (unsigned short*)attn_region;

    convert_bf16<<<6144, 256, 0, stream>>>(x, xb, 6291456);
    convert_bf16<<<1728, 256, 0, stream>>>(qkvw, wb, 1769472);
    convert_bf16<<<576, 256, 0, stream>>>(outw, outwb, 589824);
    qkv_gemm_mfma<<<dim3(18, 64), 256, 0, stream>>>(xb, wb, qf, kf, vv);
    band_partial<<<48 * 8, 256, 0, stream>>>(kf, vv, pkv, pks);
    band_reduce<<<48 * 4, 256, 0, stream>>>(pkv, pks, aq, kvs, ksums, aout);
    combine<<<48 * 32, 256, 0, stream>>>(qf, kf, vv, aq, kvs, ksums, aout, wlp, wsp, wgp, attnb);
    out_gemm_mfma<<<dim3(6, 64), 256, 0, stream>>>(attnb, outwb, (float*)d_out);
}

// Round 14
// 411.262 us; speedup vs baseline: 2.3566x; 1.0101x over previous
//
#include <hip/hip_runtime.h>
#include <hip/hip_bf16.h>

#define B_ 4
#define S_ 2048
#define D_ 768
#define H_ 12
#define HD 64

typedef __attribute__((ext_vector_type(8))) short short8;
typedef __attribute__((ext_vector_type(4))) float f32x4;

__device__ __forceinline__ float fmapf(float x) { return x > 0.f ? x + 1.f : __expf(x); }

// fp32 -> bf16 round-to-nearest-even (finite inputs only)
__device__ __forceinline__ unsigned short f2bu(float f) {
    unsigned u = __float_as_uint(f);
    u += 0x7FFFu + ((u >> 16) & 1u);
    return (unsigned short)(u >> 16);
}
__device__ __forceinline__ float bu2f(unsigned short v) {
    return __uint_as_float((unsigned)v << 16);
}

// ---------------------------------------------------------------------------
// Kernel 0: fp32 -> bf16 bulk convert (n % 4 == 0).
// ---------------------------------------------------------------------------
__global__ __launch_bounds__(256) void convert_bf16(const float* __restrict__ src,
                                                    unsigned short* __restrict__ dst,
                                                    int n) {
    int i = (blockIdx.x * 256 + threadIdx.x) * 4;
    if (i < n) {
        float4 v = *(const float4*)&src[i];
        ushort4 o;
        o.x = f2bu(v.x); o.y = f2bu(v.y); o.z = f2bu(v.z); o.w = f2bu(v.w);
        *(ushort4*)&dst[i] = o;
    }
}

// ---------------------------------------------------------------------------
// Kernel 1: qkv = x @ qkv_w.T via bf16 MFMA (16x16x32), fp32 accumulate.
// ---------------------------------------------------------------------------
__global__ __launch_bounds__(256) void qkv_gemm_mfma(const unsigned short* __restrict__ xb,
                                                     const unsigned short* __restrict__ wb,
                                                     float* __restrict__ qf,
                                                     float* __restrict__ kf,
                                                     float* __restrict__ vv) {
    __shared__ short As[128][40];  // 128 x 32 bf16, +8 pad (80B row stride)
    __shared__ short Bs[128][40];
    const int K = 768;
    int n0 = blockIdx.x * 128, m0 = blockIdx.y * 128;
    int tid = threadIdx.x, lane = tid & 63, wave = tid >> 6;
    int wm = (wave & 1) * 64, wn = (wave >> 1) * 64;
    int quad = lane >> 4, l15 = lane & 15;
    int srow = tid >> 1, scol = (tid & 1) * 16;
    f32x4 acc[4][4];
#pragma unroll
    for (int i = 0; i < 4; i++)
#pragma unroll
        for (int j = 0; j < 4; j++) acc[i][j] = 0.f;

    for (int k0 = 0; k0 < K; k0 += 32) {
        const unsigned short* xp = xb + (size_t)(m0 + srow) * K + k0 + scol;
        const unsigned short* wp = wb + (size_t)(n0 + srow) * K + k0 + scol;
        uint4 xa0 = *(const uint4*)xp;
        uint4 xa1 = *(const uint4*)(xp + 8);
        uint4 wa0 = *(const uint4*)wp;
        uint4 wa1 = *(const uint4*)(wp + 8);
        *(uint4*)&As[srow][scol] = xa0;
        *(uint4*)&As[srow][scol + 8] = xa1;
        *(uint4*)&Bs[srow][scol] = wa0;
        *(uint4*)&Bs[srow][scol + 8] = wa1;
        __syncthreads();
        short8 af[4], bfr[4];
#pragma unroll
        for (int i = 0; i < 4; i++) af[i] = *(short8*)&As[wm + i * 16 + l15][quad * 8];
#pragma unroll
        for (int j = 0; j < 4; j++) bfr[j] = *(short8*)&Bs[wn + j * 16 + l15][quad * 8];
#pragma unroll
        for (int i = 0; i < 4; i++)
#pragma unroll
            for (int j = 0; j < 4; j++)
                acc[i][j] = __builtin_amdgcn_mfma_f32_16x16x32_bf16(af[i], bfr[j], acc[i][j], 0, 0, 0);
        __syncthreads();
    }
#pragma unroll
    for (int j = 0; j < 4; j++) {
        int col = n0 + wn + j * 16 + l15;
        int t3 = col / 768;
        int r = col - t3 * 768;
        int h = r >> 6, d = r & 63;
#pragma unroll
        for (int i = 0; i < 4; i++) {
#pragma unroll
            for (int rr = 0; rr < 4; rr++) {
                int m = m0 + wm + i * 16 + quad * 4 + rr;
                int b = m >> 11, s = m & 2047;
                size_t dst = (((size_t)(b * H_ + h) * S_) + s) * HD + d;
                float val = acc[i][j][rr];
                if (t3 == 0)
                    qf[dst] = fmapf(val);
                else if (t3 == 1)
                    kf[dst] = fmapf(val);
                else
                    vv[dst] = val;
            }
        }
    }
}

// ---------------------------------------------------------------------------
// Kernel 2a: partial kv states. Grid = 48 bh * 8 chunks (256 tokens each).
// ---------------------------------------------------------------------------
__global__ __launch_bounds__(256) void band_partial(const float* __restrict__ kf,
                                                    const float* __restrict__ vv,
                                                    float* __restrict__ pkv,
                                                    float* __restrict__ pks) {
    int bh = blockIdx.x >> 3, chunk = blockIdx.x & 7;
    int sbase = chunk * 256;
    const float* kfp = kf + (size_t)bh * S_ * HD + (size_t)sbase * HD;
    const float* vp = vv + (size_t)bh * S_ * HD + (size_t)sbase * HD;
    __shared__ float kt[16][64];
    __shared__ float vt[16][64];
    int tid = threadIdx.x;
    int d = tid >> 2, eg = tid & 3, e0 = eg * 16;
    float accg[16], accs[16];
#pragma unroll
    for (int i = 0; i < 16; i++) { accg[i] = 0.f; accs[i] = 0.f; }
    float ksg = 0.f, kss = 0.f;
    for (int s0 = 0; s0 < 256; s0 += 16) {
        for (int i = tid; i < 1024; i += 256) {
            kt[i >> 6][i & 63] = kfp[(size_t)s0 * HD + i];
            vt[i >> 6][i & 63] = vp[(size_t)s0 * HD + i];
        }
        __syncthreads();
#pragma unroll 4
        for (int ss = 0; ss < 16; ss++) {
            float kd = kt[ss][d];
            bool str = ((sbase + s0 + ss) % 3) == 0;  // block-uniform
            ksg += kd;
            if (str) kss += kd;
#pragma unroll
            for (int i = 0; i < 16; i++) {
                float ve = vt[ss][e0 + i];
                accg[i] += kd * ve;
                if (str) accs[i] += kd * ve;
            }
        }
        __syncthreads();
    }
    float* pg = pkv + (size_t)blockIdx.x * 2 * 4096;
#pragma unroll
    for (int i = 0; i < 16; i++) pg[d * 64 + e0 + i] = accg[i];
#pragma unroll
    for (int i = 0; i < 16; i++) pg[4096 + d * 64 + e0 + i] = accs[i];
    if (eg == 0) {
        pks[blockIdx.x * 128 + d] = ksg;
        pks[blockIdx.x * 128 + 64 + d] = kss;
    }
}

// ---------------------------------------------------------------------------
// Kernel 2b: reduce partials + anchor outputs. Grid = 48 bh * 4 e-blocks.
// ---------------------------------------------------------------------------
__global__ __launch_bounds__(256) void band_reduce(const float* __restrict__ pkv,
                                                   const float* __restrict__ pks,
                                                   const float* __restrict__ aq,
                                                   float* __restrict__ kvs,
                                                   float* __restrict__ ksums,
                                                   float* __restrict__ aout) {
    int bh = blockIdx.x >> 2, eb = blockIdx.x & 3, e0 = eb * 16;
    int h = bh % H_;
    __shared__ float kvgL[64][17];
    __shared__ float ksgL[64];
    __shared__ float anorm[12];
    int tid = threadIdx.x;
    for (int idx = tid; idx < 1024; idx += 256) {
        int d = idx >> 4, j = idx & 15;
        float sg = 0.f, ss = 0.f;
        const float* p = pkv + (size_t)(bh * 8) * 2 * 4096 + d * 64 + e0 + j;
#pragma unroll 4
        for (int c = 0; c < 8; c++) {
            sg += p[0];
            ss += p[4096];
            p += 2 * 4096;
        }
        kvgL[d][j] = sg;
        kvs[(size_t)bh * 4096 + d * 64 + e0 + j] = ss;
    }
    if (tid < 64) {
        float sg = 0.f, ss = 0.f;
#pragma unroll 4
        for (int c = 0; c < 8; c++) {
            sg += pks[(bh * 8 + c) * 128 + tid];
            ss += pks[(bh * 8 + c) * 128 + 64 + tid];
        }
        ksgL[tid] = sg;
        if (eb == 0) ksums[bh * 64 + tid] = ss;
    }
    __syncthreads();
    if (tid < 12) {
        float nrm = 0.f;
        for (int dd = 0; dd < 64; dd++)
            nrm += fmapf(aq[h * 768 + tid * 64 + dd]) * ksgL[dd];
        anorm[tid] = fmaxf(nrm, 1e-6f);
    }
    __syncthreads();
    if (tid < 192) {
        int a = tid >> 4, j = tid & 15;
        float acc = 0.f;
        for (int dd = 0; dd < 64; dd++)
            acc += fmapf(aq[h * 768 + a * 64 + dd]) * kvgL[dd][j];
        aout[(size_t)bh * 768 + a * 64 + e0 + j] = acc / anorm[a];
    }
}

// ---------------------------------------------------------------------------
// Kernel 3: combine via MFMA. Per 64-token tile:
//  phase A (MFMA): qk_local = qf @ kft^T (64x80, band extracted),
//                  [qkg | ns] = qf @ [anchors; ksum]^T (64x16, ksum = col 12)
//  phase B (MFMA): os = qf @ kvs (64x64), epilogue fused per 16x16 tile so
//                  only 4 acc VGPRs live (r11/r12 VGPR lesson).
// All MFMA inputs bf16 in LDS; layouts identical to the proven qkv kernel
// (A=[m][k], B=[n][k], b128 frag reads). LDS ~42.4 KB -> 3 blocks/CU.
// ---------------------------------------------------------------------------
__global__ __launch_bounds__(256) void combine(const float* __restrict__ qf,
                                               const float* __restrict__ kf,
                                               const float* __restrict__ vv,
                                               const float* __restrict__ aq,
                                               const float* __restrict__ kvs,
                                               const float* __restrict__ ksums,
                                               const float* __restrict__ aout,
                                               const float* __restrict__ wlp,
                                               const float* __restrict__ wsp,
                                               const float* __restrict__ wgp,
                                               unsigned short* __restrict__ attnb) {
    __shared__ __attribute__((aligned(16))) unsigned short qftb[64][72];
    __shared__ __attribute__((aligned(16))) unsigned short kftb[80][72];
    __shared__ __attribute__((aligned(16))) unsigned short kvsbT[64][72];  // [e][d]
    __shared__ __attribute__((aligned(16))) unsigned short aqfb[16][72];   // rows 0-11 anchors, 12 ksum, 13-15 zero
    __shared__ float aoutL[12][68];
    __shared__ float qkl[64][12];
    __shared__ float qkg[64][16];
    __shared__ float nl[64], ng[64], ns[64];
    int bh = blockIdx.x >> 5, stile = blockIdx.x & 31;
    int b = bh / H_, h = bh % H_;
    int s0 = stile * 64;
    int tid = threadIdx.x, lane = tid & 63, wave = tid >> 6;
    int quad = lane >> 4, l15 = lane & 15;
    const float* qfp = qf + (size_t)bh * S_ * HD;
    const float* kfp = kf + (size_t)bh * S_ * HD;
    const float* vp = vv + (size_t)bh * S_ * HD;
    float a0 = wlp[0], a1 = wsp[0], a2 = wgp[0];
    float mx = fmaxf(a0, fmaxf(a1, a2));
    float ew0 = __expf(a0 - mx), ew1 = __expf(a1 - mx), ew2 = __expf(a2 - mx);
    float inv = 1.f / (ew0 + ew1 + ew2);
    float wl = ew0 * inv, wsb = ew1 * inv, wg = ew2 * inv;
    // stage bf16 tiles
    for (int i = tid; i < 4096; i += 256) {
        int r = i >> 6, c = i & 63;
        qftb[r][c] = f2bu(qfp[(size_t)(s0 + r) * HD + c]);
        kvsbT[c][r] = f2bu(kvs[(size_t)bh * 4096 + i]);  // transpose -> [e][d]
    }
    for (int i = tid; i < 80 * 64; i += 256) {
        int row = i >> 6, c = i & 63;
        int gs = s0 + row - 6;
        float kv_ = (row < 75 && gs >= 0 && gs < S_) ? kfp[(size_t)gs * HD + c] : 1.0f;
        kftb[row][c] = f2bu(kv_);
    }
    for (int i = tid; i < 1024; i += 256) {
        int a = i >> 6, dd = i & 63;
        float v_;
        if (a < 12) v_ = fmapf(aq[h * 768 + a * 64 + dd]);
        else if (a == 12) v_ = ksums[bh * 64 + dd];
        else v_ = 0.f;
        aqfb[a][dd] = f2bu(v_);
    }
    for (int i = tid; i < 768; i += 256) aoutL[i >> 6][i & 63] = aout[(size_t)bh * 768 + i];
    __syncthreads();
    // phase A: 20 local tiles + 4 anchor tiles = 24, round-robin over 4 waves
    for (int tt = wave; tt < 24; tt += 4) {
        f32x4 c = {0.f, 0.f, 0.f, 0.f};
        if (tt < 20) {
            int ti = tt / 5, tj = tt % 5;
#pragma unroll
            for (int kk = 0; kk < 2; kk++) {
                short8 afr = *(short8*)&qftb[ti * 16 + l15][kk * 32 + quad * 8];
                short8 bfr = *(short8*)&kftb[tj * 16 + l15][kk * 32 + quad * 8];
                c = __builtin_amdgcn_mfma_f32_16x16x32_bf16(afr, bfr, c, 0, 0, 0);
            }
            int col = tj * 16 + l15;
#pragma unroll
            for (int rr = 0; rr < 4; rr++) {
                int token = ti * 16 + quad * 4 + rr;
                int which = col - token;
                if (which >= 0 && which < 12) qkl[token][which] = c[rr];
            }
        } else {
            int ti = tt - 20;
#pragma unroll
            for (int kk = 0; kk < 2; kk++) {
                short8 afr = *(short8*)&qftb[ti * 16 + l15][kk * 32 + quad * 8];
                short8 bfr = *(short8*)&aqfb[l15][kk * 32 + quad * 8];
                c = __builtin_amdgcn_mfma_f32_16x16x32_bf16(afr, bfr, c, 0, 0, 0);
            }
#pragma unroll
            for (int rr = 0; rr < 4; rr++) {
                int token = ti * 16 + quad * 4 + rr;
                qkg[token][l15] = c[rr];
            }
        }
    }
    __syncthreads();
    if (tid < 64) {
        float sl = 0.f, sg = 0.f;
#pragma unroll
        for (int j = 0; j < 12; j++) { sl += qkl[tid][j]; sg += qkg[tid][j]; }
        nl[tid] = fmaxf(sl, 1e-6f);
        ng[tid] = fmaxf(sg, 1e-6f);
        ns[tid] = fmaxf(qkg[tid][12], 1e-6f);
    }
    __syncthreads();
    // phase B: os tiles (row tile = wave, col tiles 0..3), fused epilogue
#pragma unroll
    for (int j2 = 0; j2 < 4; j2++) {
        f32x4 c = {0.f, 0.f, 0.f, 0.f};
#pragma unroll
        for (int kk = 0; kk < 2; kk++) {
            short8 afr = *(short8*)&qftb[wave * 16 + l15][kk * 32 + quad * 8];
            short8 bfr = *(short8*)&kvsbT[j2 * 16 + l15][kk * 32 + quad * 8];
            c = __builtin_amdgcn_mfma_f32_16x16x32_bf16(afr, bfr, c, 0, 0, 0);
        }
        int e = j2 * 16 + l15;
#pragma unroll
        for (int rr = 0; rr < 4; rr++) {
            int token = wave * 16 + quad * 4 + rr;
            float ol = 0.f;
#pragma unroll
            for (int j = 0; j < 12; j++) {
                int gs = s0 + token + j - 6;
                float vval = (gs >= 0 && gs < S_) ? vp[(size_t)gs * HD + e] : 0.f;
                ol += qkl[token][j] * vval;
            }
            float og = 0.f;
#pragma unroll
            for (int a = 0; a < 12; a++) og += qkg[token][a] * aoutL[a][e];
            float res = wl * ol / nl[token] + wsb * c[rr] / ns[token] + wg * og / ng[token];
            attnb[((size_t)(b * S_ + s0 + token)) * 768 + h * 64 + e] = f2bu(res);
        }
    }
}

// ---------------------------------------------------------------------------
// Kernel 4: out = attn(bf16) @ out_w.T via bf16 MFMA -> fp32 out.
// ---------------------------------------------------------------------------
__global__ __launch_bounds__(256) void out_gemm_mfma(const unsigned short* __restrict__ attnb,
                                                     const unsigned short* __restrict__ wb,
                                                     float* __restrict__ out) {
    __shared__ short As[128][40];
    __shared__ short Bs[128][40];
    const int K = 768;
    int n0 = blockIdx.x * 128, m0 = blockIdx.y * 128;
    int tid = threadIdx.x, lane = tid & 63, wave = tid >> 6;
    int wm = (wave & 1) * 64, wn = (wave >> 1) * 64;
    int quad = lane >> 4, l15 = lane & 15;
    int srow = tid >> 1, scol = (tid & 1) * 16;
    f32x4 acc[4][4];
#pragma unroll
    for (int i = 0; i < 4; i++)
#pragma unroll
        for (int j = 0; j < 4; j++) acc[i][j] = 0.f;

    for (int k0 = 0; k0 < K; k0 += 32) {
        const unsigned short* ap = attnb + (size_t)(m0 + srow) * K + k0 + scol;
        const unsigned short* wp = wb + (size_t)(n0 + srow) * K + k0 + scol;
        uint4 a0 = *(const uint4*)ap;
        uint4 a1 = *(const uint4*)(ap + 8);
        uint4 w0 = *(const uint4*)wp;
        uint4 w1 = *(const uint4*)(wp + 8);
        *(uint4*)&As[srow][scol] = a0;
        *(uint4*)&As[srow][scol + 8] = a1;
        *(uint4*)&Bs[srow][scol] = w0;
        *(uint4*)&Bs[srow][scol + 8] = w1;
        __syncthreads();
        short8 af[4], bfr[4];
#pragma unroll
        for (int i = 0; i < 4; i++) af[i] = *(short8*)&As[wm + i * 16 + l15][quad * 8];
#pragma unroll
        for (int j = 0; j < 4; j++) bfr[j] = *(short8*)&Bs[wn + j * 16 + l15][quad * 8];
#pragma unroll
        for (int i = 0; i < 4; i++)
#pragma unroll
            for (int j = 0; j < 4; j++)
                acc[i][j] = __builtin_amdgcn_mfma_f32_16x16x32_bf16(af[i], bfr[j], acc[i][j], 0, 0, 0);
        __syncthreads();
    }
#pragma unroll
    for (int j = 0; j < 4; j++) {
        int col = n0 + wn + j * 16 + l15;
#pragma unroll
        for (int i = 0; i < 4; i++) {
#pragma unroll
            for (int rr = 0; rr < 4; rr++) {
                int m = m0 + wm + i * 16 + quad * 4 + rr;
                out[(size_t)m * 768 + col] = acc[i][j][rr];
            }
        }
    }
}

extern "C" void kernel_launch(void* const* d_in, const int* in_sizes, int n_in,
                              void* d_out, int out_size, void* d_ws, size_t ws_size,
                              hipStream_t stream) {
    const float* x = (const float*)d_in[0];
    const float* qkvw = (const float*)d_in[1];
    const float* outw = (const float*)d_in[2];
    const float* aq = (const float*)d_in[3];
    const float* wlp = (const float*)d_in[4];
    const float* wsp = (const float*)d_in[5];
    const float* wgp = (const float*)d_in[6];

    float* ws = (float*)d_ws;
    const size_t NBH = (size_t)B_ * H_ * S_ * HD;  // 6,291,456
    float* qf = ws;
    float* kf = qf + NBH;
    float* vv = kf + NBH;
    float* attn_region = vv + NBH;       // NBH floats; multi-use scratch
    float* kvs = attn_region + NBH;      // 48*4096
    float* ksums = kvs + 48 * 4096;      // 48*64
    float* aout = ksums + 48 * 64;       // 48*768
    // Lifetimes inside attn_region (NBH floats):
    //  [0, 3145728)           xb (bf16 x)      : convert .. qkv_gemm
    //  [3145728, 4030464)     wb (bf16 qkv_w)  : convert .. qkv_gemm
    //  [4030464, 4325376)     outwb (bf16)     : convert .. out_gemm
    //  [0, 3145728)           pkv              : band_partial .. band_reduce
    //  [3145728, 3194880)     pks              : band_partial .. band_reduce
    //  [0, 3145728)           attnb (bf16 attn): combine .. out_gemm
    unsigned short* xb = (unsigned short*)attn_region;
    unsigned short* wb = (unsigned short*)(attn_region + 3145728);
    unsigned short* outwb = (unsigned short*)(attn_region + 3145728 + 884736);
    float* pkv = attn_region;
    float* pks = attn_region + 3145728;
    unsigned short* attnb = (unsigned short*)attn_region;

    convert_bf16<<<6144, 256, 0, stream>>>(x, xb, 6291456);
    convert_bf16<<<1728, 256, 0, stream>>>(qkvw, wb, 1769472);
    convert_bf16<<<576, 256, 0, stream>>>(outw, outwb, 589824);
    qkv_gemm_mfma<<<dim3(18, 64), 256, 0, stream>>>(xb, wb, qf, kf, vv);
    band_partial<<<48 * 8, 256, 0, stream>>>(kf, vv, pkv, pks);
    band_reduce<<<48 * 4, 256, 0, stream>>>(pkv, pks, aq, kvs, ksums, aout);
    combine<<<48 * 32, 256, 0, stream>>>(qf, kf, vv, aq, kvs, ksums, aout, wlp, wsp, wgp, attnb);
    out_gemm_mfma<<<dim3(6, 64), 256, 0, stream>>>(attnb, outwb, (float*)d_out);
}